// Round 8
// baseline (729.146 us; speedup 1.0000x reference)
//
#include <hip/hip_runtime.h>

// EmbeddingLSQ: out[t,d] = (idx[t]==0) ? 0 : rint(clamp(W[d,idx[t]]/a,-8,7))*a
// idx[t] = position of the 1.0 in one-hot row x[t,:].
//
// 1 wave per token. SOFTWARE-PIPELINED scan: window k+1's 8 loads are issued
// BEFORE the ballot-exit check of window k (fully unrolled, SSA double
// buffer), so the check needs only vmcnt(8) — the wave never drains its
// memory pipe between windows. This is the structural difference between
// our previous ~1.8 TB/s scan (vmcnt(0) drain per 8 KB window) and the
// harness fills at 6.4 TB/s.  Cost: one window (8 KB/token) of overshoot.
// Phase 2: 16 scattered w gathers/lane + fp32 LSQ quant + coalesced stores.

typedef float        v4f __attribute__((ext_vector_type(4)));
typedef unsigned int v4u __attribute__((ext_vector_type(4)));
typedef unsigned int u32;

constexpr int VOCAB  = 32000;
constexpr int DIM    = 1024;
constexpr int TOKENS = 4096;
constexpr int V4     = VOCAB / 4;        // 8000 16B chunks per x row
constexpr int WPT    = 8;                // chunks/lane/window (8 KB window)
constexpr int WIN    = 64 * WPT;         // 512 chunks per window
constexpr int NWIN   = V4 / WIN;         // 15 full windows
constexpr int TAILB  = NWIN * WIN;       // 7680
constexpr int TAILC  = (V4 - TAILB) / 64;// 5 tail chunks per lane

__device__ __forceinline__ int word_of(v4u c) {
    return c.x ? 0 : (c.y ? 1 : (c.z ? 2 : 3));
}
__device__ __forceinline__ u32 nz(v4u c) { return c.x | c.y | c.z | c.w; }

__global__ __launch_bounds__(64) void emb_lsq_kernel(
    const float* __restrict__ x,
    const float* __restrict__ w,
    const float* __restrict__ alpha,
    float* __restrict__ out)
{
    const int lane = threadIdx.x;
    const int t    = blockIdx.x;

    // ---- Phase 1: pipelined ballot-exit scan ----
    const v4u* xr = reinterpret_cast<const v4u*>(x + (size_t)t * VOCAB);
    int  cand = -1;
    bool done = false;

    v4u A[WPT], B[WPT];
    #pragma unroll
    for (int j = 0; j < WPT; ++j) A[j] = xr[lane + 64 * j];   // window 0

    #pragma unroll
    for (int k = 0; k < NWIN; ++k) {
        if (k + 1 < NWIN) {               // issue window k+1 BEFORE checking k
            #pragma unroll
            for (int j = 0; j < WPT; ++j)
                B[j] = xr[(k + 1) * WIN + lane + 64 * j];
        }
        u32 m = 0;                        // check window k (waits only its own
        #pragma unroll                    //  8 loads; k+1 stays in flight)
        for (int j = 0; j < WPT; ++j) m |= nz(A[j]);
        if (__ballot(m != 0)) {
            if (m) {                      // at most one lane: decode position
                #pragma unroll
                for (int j = 0; j < WPT; ++j)
                    if (nz(A[j])) cand = 4 * (k * WIN + lane + 64 * j) + word_of(A[j]);
            }
            done = true;
            break;
        }
        #pragma unroll
        for (int j = 0; j < WPT; ++j) A[j] = B[j];   // SSA after full unroll
    }
    if (!done) {                          // tail: chunks 7680..7999 (rare, 4%)
        #pragma unroll
        for (int j = 0; j < TAILC; ++j) {
            const int c = TAILB + lane + 64 * j;
            v4u v = xr[c];
            if (nz(v)) cand = 4 * c + word_of(v);
        }
    }
    const unsigned long long msk = __ballot(cand >= 0);
    const int idx = msk ? __shfl(cand, (int)__ffsll(msk) - 1) : 0;

    // ---- Phase 2: gather w column + LSQ fake-quant + coalesced stores ----
    v4f* orow = reinterpret_cast<v4f*>(out + (size_t)t * DIM);
    if (idx <= 0) {                       // PAD_IDX -> zero row
        v4f z = 0.f;
        #pragma unroll
        for (int j = 0; j < 4; ++j) orow[lane + 64 * j] = z;
    } else {
        const float a = alpha[0];
        const size_t col = (size_t)idx;
        float wv[16];
        #pragma unroll
        for (int j = 0; j < 4; ++j) {     // 16 independent gathers in flight
            const int d0 = 4 * lane + 256 * j;
            wv[4*j+0] = w[(size_t)(d0 + 0) * VOCAB + col];
            wv[4*j+1] = w[(size_t)(d0 + 1) * VOCAB + col];
            wv[4*j+2] = w[(size_t)(d0 + 2) * VOCAB + col];
            wv[4*j+3] = w[(size_t)(d0 + 3) * VOCAB + col];
        }
        #pragma unroll
        for (int j = 0; j < 4; ++j) {
            v4f q;
            q.x = rintf(fminf(fmaxf(wv[4*j+0] / a, -8.f), 7.f)) * a;
            q.y = rintf(fminf(fmaxf(wv[4*j+1] / a, -8.f), 7.f)) * a;
            q.z = rintf(fminf(fmaxf(wv[4*j+2] / a, -8.f), 7.f)) * a;
            q.w = rintf(fminf(fmaxf(wv[4*j+3] / a, -8.f), 7.f)) * a;
            orow[lane + 64 * j] = q;      // 1 KB coalesced store per instr
        }
    }
}

extern "C" void kernel_launch(void* const* d_in, const int* in_sizes, int n_in,
                              void* d_out, int out_size, void* d_ws, size_t ws_size,
                              hipStream_t stream) {
    const float* x     = (const float*)d_in[0];   // [TOKENS, VOCAB]
    const float* w     = (const float*)d_in[1];   // [DIM, VOCAB]
    const float* alpha = (const float*)d_in[2];   // [1]
    float* out         = (float*)d_out;           // [TOKENS, DIM]

    emb_lsq_kernel<<<TOKENS, 64, 0, stream>>>(x, w, alpha, out);
}